// Round 26
// baseline (136.634 us; speedup 1.0000x reference)
//
#include <hip/hip_runtime.h>
#include <hip/hip_bf16.h>

typedef unsigned short u16;
typedef __bf16 bf16x8 __attribute__((ext_vector_type(8)));
typedef float f32x4 __attribute__((ext_vector_type(4)));

#define S_LEN 2048
#define HID 2048
#define NH 32
#define NKV 8
#define HD 64

// native RTNE f32->bf16 (single v_cvt op; compiler packs pairs)
__device__ inline u16 f2bf(float x) {
    __bf16 h = (__bf16)x;
    return __builtin_bit_cast(u16, h);
}

__device__ inline void gload_lds16(const u16* g, u16* l) {
    __builtin_amdgcn_global_load_lds((const __attribute__((address_space(1))) unsigned int*)g,
                                     (__attribute__((address_space(3))) unsigned int*)l, 16, 0, 0);
}

// ---------------- fp32 -> bf16 convert, all 5 tensors in one launch ----------------
__global__ void cvt_all(const float* __restrict__ h, const float* __restrict__ wq,
                        const float* __restrict__ wk, const float* __restrict__ wv,
                        const float* __restrict__ wo,
                        u16* __restrict__ hb, u16* __restrict__ wqkv, u16* __restrict__ wob) {
    int i = blockIdx.x * blockDim.x + threadIdx.x;   // float4 index, total 3670016
    const float* src; u16* dst; int o;
    if (i < 1048576)      { src = h;  dst = hb;   o = i; }
    else if (i < 2097152) { src = wq; dst = wqkv; o = i - 1048576; }
    else if (i < 2359296) { src = wk; dst = wqkv + (size_t)2048 * 2048; o = i - 2097152; }
    else if (i < 2621440) { src = wv; dst = wqkv + (size_t)2560 * 2048; o = i - 2359296; }
    else                  { src = wo; dst = wob;  o = i - 2621440; }
    float4 v = ((const float4*)src)[o];
    ushort4 u;
    u.x = f2bf(v.x); u.y = f2bf(v.y); u.z = f2bf(v.z); u.w = f2bf(v.w);
    ((ushort4*)dst)[o] = u;
}

// ---------------- GEMM: 64x128 tile, BK=32, 3-buffer counted-vmcnt pipeline ----------------
// Depth-2 prefetch: stage(t+2) issued each iter; barrier waits vmcnt(3) (stage(t) landed,
// stage(t+1) stays in flight) -> ~2 steps of latency cover, never drains to 0 mid-loop.
// LDS XOR-swizzle via source-permute (read col = g^(r16&3)).
// mode 1: store fp32 row-major (ldc)
// mode 3: fused QKV epilogue with RoPE; K,V scattered into MFMA-fragment-packed layouts.
__global__ __launch_bounds__(256) void gemm_bt(const u16* __restrict__ A,
                                               const u16* __restrict__ B,
                                               void* __restrict__ Cv,
                                               int K_, int mode, int ldc,
                                               const float* __restrict__ cosp,
                                               const float* __restrict__ sinp) {
    __shared__ u16 As[3][64 * 32];
    __shared__ u16 Bs[3][128 * 32];
    const int t = threadIdx.x;
    // XCD-aware bijective swizzle (nwg % 8 == 0 for both call sites)
    const int nwg = gridDim.x * gridDim.y;
    const int orig = blockIdx.y * gridDim.x + blockIdx.x;
    const int wgid = (orig & 7) * (nwg >> 3) + (orig >> 3);
    const int bm = wgid % gridDim.x, bn = wgid / gridDim.x;
    const int lane = t & 63, w = t >> 6;
    const int wr2 = (w >> 1) * 32, wc2 = (w & 1) * 64;
    const int g = lane >> 4, r16 = lane & 15;
    f32x4 acc[2][4] = {};

    // staging: lane ell writes LDS slot ell*16B; source col permuted for the swizzled layout
    const int srowA = w * 16 + (lane >> 2);
    const int srowB = w * 32 + (lane >> 2);
    const int scol = (((lane & 3) ^ ((lane >> 2) & 3))) * 8;   // swizzled source col
    const u16* Ap = A + (size_t)(bm * 64 + srowA) * K_ + scol;
    const u16* Bp = B + (size_t)(bn * 128 + srowB) * K_ + scol;
    const int aoff = w * 512;    // 16 rows * 32
    const int boff = w * 1024;   // 32 rows * 32

    // prologue: stage tiles 0 and 1
    gload_lds16(Ap, &As[0][aoff]);
    gload_lds16(Bp, &Bs[0][boff]);
    gload_lds16(Bp + (size_t)16 * K_, &Bs[0][boff + 512]);
    gload_lds16(Ap + 32, &As[1][aoff]);
    gload_lds16(Bp + 32, &Bs[1][boff]);
    gload_lds16(Bp + 32 + (size_t)16 * K_, &Bs[1][boff + 512]);

    int cur = 0;
    for (int kt = 0; kt < K_; kt += 32) {
        // wait for stage(t); keep stage(t+1)'s 3 loads in flight (drain only on last iter)
        if (kt + 32 < K_) asm volatile("s_waitcnt vmcnt(3)" ::: "memory");
        else              asm volatile("s_waitcnt vmcnt(0)" ::: "memory");
        __builtin_amdgcn_s_barrier();   // buf[cur] ready for all; prev iter's reads complete
        const int nxt2 = kt + 64;
        if (nxt2 < K_) {   // stage(t+2) into the buffer freed at iter t-1
            const int nb = (cur >= 1) ? cur - 1 : 2;   // (cur+2)%3
            gload_lds16(Ap + nxt2, &As[nb][aoff]);
            gload_lds16(Bp + nxt2, &Bs[nb][boff]);
            gload_lds16(Bp + nxt2 + (size_t)16 * K_, &Bs[nb][boff + 512]);
        }
        bf16x8 af[2], bfr[4];
        const int cg = (g ^ (r16 & 3)) * 8;   // swizzled read col
#pragma unroll
        for (int i = 0; i < 2; i++) af[i] = *(const bf16x8*)(&As[cur][(wr2 + i * 16 + r16) * 32 + cg]);
#pragma unroll
        for (int j = 0; j < 4; j++) bfr[j] = *(const bf16x8*)(&Bs[cur][(wc2 + j * 16 + r16) * 32 + cg]);
#pragma unroll
        for (int i = 0; i < 2; i++)
#pragma unroll
            for (int j = 0; j < 4; j++)
                acc[i][j] = __builtin_amdgcn_mfma_f32_16x16x32_bf16(af[i], bfr[j], acc[i][j], 0, 0, 0);
        cur = (cur < 2) ? cur + 1 : 0;
    }

    u16* qb_ = (u16*)Cv;
    u16* kb_ = qb_ + (size_t)2048 * 2048;
    u16* vt_ = kb_ + (size_t)512 * 2048;
    if (mode == 1) {
#pragma unroll
        for (int i = 0; i < 2; i++)
#pragma unroll
            for (int j = 0; j < 4; j++)
#pragma unroll
                for (int r = 0; r < 4; r++) {
                    int row = bm * 64 + wr2 + i * 16 + g * 4 + r;
                    int col = bn * 128 + wc2 + j * 16 + r16;
                    ((float*)Cv)[(size_t)row * ldc + col] = acc[i][j][r];
                }
    } else {
        const int cbase = bn * 128 + wc2;   // 64-aligned => wave span = one head
        if (cbase < 2560) {
            // q or k region: fused RoPE on fp32 accumulators (exact pre-round)
            const float scl = (cbase < 2048) ? 0.125f * 1.44269504f : 1.0f;
#pragma unroll
            for (int i = 0; i < 2; i++)
#pragma unroll
                for (int r = 0; r < 4; r++) {
                    int row = bm * 64 + wr2 + i * 16 + g * 4 + r;
#pragma unroll
                    for (int j = 0; j < 2; j++) {
                        int c0 = cbase + j * 16 + r16;
                        int iin = c0 & 63;                 // in-head dim, < 32
                        float x1 = acc[i][j][r], x2 = acc[i][j + 2][r];
                        float cA = cosp[row * 64 + iin],      sA = sinp[row * 64 + iin];
                        float cB = cosp[row * 64 + iin + 32], sB = sinp[row * 64 + iin + 32];
                        u16 o1 = f2bf((x1 * cA - x2 * sA) * scl);
                        u16 o2 = f2bf((x2 * cB + x1 * sB) * scl);
                        if (cbase < 2048) {
                            qb_[(size_t)row * 2048 + c0] = o1;
                            qb_[(size_t)row * 2048 + c0 + 32] = o2;
                        } else {
                            // K fragment-packed: frag row fr = row>>4, lane = gq*16 + (row&15)
                            int c = c0 - 2048;
                            int kvh_w = c >> 6, iin2 = c & 63;
                            int gq = (iin2 >> 3) & 3, e = iin2 & 7;
                            int fr = row >> 4, r16w = row & 15;
                            size_t base = ((size_t)(kvh_w * 128 + fr) * 2) * 512 + (size_t)(gq * 16 + r16w) * 8 + e;
                            kb_[base] = o1;            // d=0 (iin<32)
                            kb_[base + 512] = o2;      // d=1 (iin+32)
                        }
                    }
                }
        } else {
            // V fragment-packed: dg = col-2560; s = row
#pragma unroll
            for (int i = 0; i < 2; i++)
#pragma unroll
                for (int j = 0; j < 4; j++)
#pragma unroll
                    for (int r = 0; r < 4; r++) {
                        int row = bm * 64 + wr2 + i * 16 + g * 4 + r;
                        int col = cbase + j * 16 + r16;
                        int dg = col - 2560;
                        int kvh_w = dg >> 6, dblk_w = (dg >> 4) & 3, r16v = dg & 15;
                        int fr32 = row >> 5, gv = (row >> 3) & 3, e = row & 7;
                        vt_[((size_t)((kvh_w * 64 + fr32) * 4 + dblk_w)) * 512 + (size_t)(gv * 16 + r16v) * 8 + e] = f2bf(acc[i][j][r]);
                    }
        }
    }
}

// ---------------- Flash attention (causal, GQA): paired units, packed K/V ----------------
// R24-proven: wave-linear 1KB fragment loads (8 lines/instr), shift-free softmax,
// raw exp2, l rides MFMA ones-column, kvh-per-XCD, paired units (63-p then p).
__global__ __launch_bounds__(64) void attn_kernel(const u16* __restrict__ q,
                                                  const u16* __restrict__ kp_all,
                                                  const u16* __restrict__ vp_all,
                                                  u16* __restrict__ attn) {
    __shared__ u16 P[2][16][136];  // [frag][qrow][kcol]
    const int bid = blockIdx.x;
    const int kvh = bid & 7;                       // XCD-local KV slice
    const int h = kvh * 4 + ((bid >> 3) & 3);
    const int p = bid >> 5;                        // 0..31 pair index
    const int lane = threadIdx.x & 63;
    const int g = lane >> 4, r16 = lane & 15;

    const u16* kp = kp_all + (size_t)kvh * 131072;   // 128 frags * 2 d * 512
    const u16* vp = vp_all + (size_t)kvh * 131072;   // 64 frags * 4 dblk * 512

    bf16x8 vone;
#pragma unroll
    for (int j = 0; j < 8; j++) vone[j] = (__bf16)1.0f;

    for (int u = 0; u < 2; u++) {
        const int qblk = u ? p : 63 - p;   // heavy unit first
        const int qrow0 = qblk * 32;

        bf16x8 qf[2][2];
#pragma unroll
        for (int fi = 0; fi < 2; fi++)
#pragma unroll
            for (int d = 0; d < 2; d++)
                qf[fi][d] = *(const bf16x8*)(q + (size_t)(qrow0 + fi * 16 + r16) * (NH * HD) + h * HD + d * 32 + g * 8);

        f32x4 o[2][4] = {};
        f32x4 ol[2] = {};   // l ridden as an MFMA ones-column

        const int last = (qrow0 >> 7) << 7;   // last 128-wide KV tile start

        // prologue: load K tile 0 (packed: frag fr, lane-linear)
        bf16x8 kA[4][2], kB[4][2];
#pragma unroll
        for (int s4 = 0; s4 < 4; s4++)
#pragma unroll
            for (int d = 0; d < 2; d++) {
                kA[s4][d] = *(const bf16x8*)(kp + ((size_t)(s4 * 2 + d)) * 512 + lane * 8);
                kB[s4][d] = *(const bf16x8*)(kp + ((size_t)((4 + s4) * 2 + d)) * 512 + lane * 8);
            }

        for (int kv = 0; kv <= last; kv += 128) {
            const bool diag = (kv == last);
            f32x4 sacc[2][8] = {};
            // ---- QK^T: 32 MFMA on registered K tile ----
#pragma unroll
            for (int s4 = 0; s4 < 4; s4++)
#pragma unroll
                for (int fi = 0; fi < 2; fi++)
#pragma unroll
                    for (int d = 0; d < 2; d++)
                        sacc[fi][s4] = __builtin_amdgcn_mfma_f32_16x16x32_bf16(qf[fi][d], kA[s4][d], sacc[fi][s4], 0, 0, 0);
#pragma unroll
            for (int s4 = 0; s4 < 4; s4++)
#pragma unroll
                for (int fi = 0; fi < 2; fi++)
#pragma unroll
                    for (int d = 0; d < 2; d++)
                        sacc[fi][4 + s4] = __builtin_amdgcn_mfma_f32_16x16x32_bf16(qf[fi][d], kB[s4][d], sacc[fi][4 + s4], 0, 0, 0);
            // ---- prefetch next K tile (packed) ----
            if (kv + 128 <= last) {
                const int nf = (kv + 128) >> 4;   // next tile's first frag
#pragma unroll
                for (int s4 = 0; s4 < 4; s4++)
#pragma unroll
                    for (int d = 0; d < 2; d++) {
                        kA[s4][d] = *(const bf16x8*)(kp + ((size_t)((nf + s4) * 2 + d)) * 512 + lane * 8);
                        kB[s4][d] = *(const bf16x8*)(kp + ((size_t)((nf + 4 + s4) * 2 + d)) * 512 + lane * 8);
                    }
            }
            // ---- V loads (packed): frag fv = kv/32 + kq ----
            bf16x8 vf[4][4];
            const int fv0 = kv >> 5;
#pragma unroll
            for (int kq = 0; kq < 4; kq++)
#pragma unroll
                for (int dblk = 0; dblk < 4; dblk++)
                    vf[kq][dblk] = *(const bf16x8*)(vp + ((size_t)((fv0 + kq) * 4 + dblk)) * 512 + lane * 8);
            // ---- causal mask (diagonal super-tile only): exp2(-1e30) -> 0 ----
            if (diag) {
#pragma unroll
                for (int fi = 0; fi < 2; fi++)
#pragma unroll
                    for (int sub = 0; sub < 8; sub++)
#pragma unroll
                        for (int r = 0; r < 4; r++) {
                            int col = kv + sub * 16 + r16;
                            int row = qrow0 + fi * 16 + g * 4 + r;
                            if (col > row) sacc[fi][sub][r] = -1e30f;
                        }
            }
            // ---- shift-free softmax numerator: P = exp2(S) straight to LDS ----
#pragma unroll
            for (int fi = 0; fi < 2; fi++)
#pragma unroll
                for (int sub = 0; sub < 8; sub++)
#pragma unroll
                    for (int r = 0; r < 4; r++)
                        P[fi][g * 4 + r][sub * 16 + r16] = f2bf(__builtin_amdgcn_exp2f(sacc[fi][sub][r]));
            // ---- PV: 40 MFMA (4 dblk + 1 ones-column per kq per frag) ----
#pragma unroll
            for (int fi = 0; fi < 2; fi++)
#pragma unroll
                for (int kq = 0; kq < 4; kq++) {
                    bf16x8 pf = *(const bf16x8*)(&P[fi][r16][kq * 32 + g * 8]);
                    ol[fi] = __builtin_amdgcn_mfma_f32_16x16x32_bf16(pf, vone, ol[fi], 0, 0, 0);
#pragma unroll
                    for (int dblk = 0; dblk < 4; dblk++)
                        o[fi][dblk] = __builtin_amdgcn_mfma_f32_16x16x32_bf16(pf, vf[kq][dblk], o[fi][dblk], 0, 0, 0);
                }
        }
        // ---- unit epilogue ----
#pragma unroll
        for (int fi = 0; fi < 2; fi++) {
            float inv[4];
#pragma unroll
            for (int r = 0; r < 4; r++) inv[r] = 1.0f / ol[fi][r];
#pragma unroll
            for (int dblk = 0; dblk < 4; dblk++)
#pragma unroll
                for (int r = 0; r < 4; r++) {
                    float val = o[fi][dblk][r] * inv[r];
                    attn[(size_t)(qrow0 + fi * 16 + g * 4 + r) * (NH * HD) + h * HD + dblk * 16 + r16] = f2bf(val);
                }
        }
    }
}

extern "C" void kernel_launch(void* const* d_in, const int* in_sizes, int n_in,
                              void* d_out, int out_size, void* d_ws, size_t ws_size,
                              hipStream_t stream) {
    const float* hidden = (const float*)d_in[0];
    const float* Wq = (const float*)d_in[1];
    const float* Wk = (const float*)d_in[2];
    const float* Wv = (const float*)d_in[3];
    const float* Wo = (const float*)d_in[4];
    const float* cosp = (const float*)d_in[5];
    const float* sinp = (const float*)d_in[6];
    float* out = (float*)d_out;

    char* ws = (char*)d_ws;
    u16* hb   = (u16*)(ws);                        // 8 MB  [2048,2048]
    u16* wqkv = (u16*)(ws + ((size_t)8 << 20));    // 12 MB [3072,2048] (Wq;Wk;Wv)
    u16* wob  = (u16*)(ws + ((size_t)20 << 20));   // 8 MB  [2048,2048]
    u16* qbuf = (u16*)(ws + ((size_t)28 << 20));   // 8 MB  [2048,2048]  (kpak, vpak follow)
    u16* kpak = qbuf + (size_t)2048 * 2048;        // 2 MB  fragment-packed K
    u16* vpak = kpak + (size_t)512 * 2048;         // 2 MB  fragment-packed V
    u16* attn = (u16*)(ws + ((size_t)40 << 20));   // 8 MB  [2048,2048]

    // single fused fp32->bf16 conversion launch
    cvt_all<<<14336, 256, 0, stream>>>(hidden, Wq, Wk, Wv, Wo, hb, wqkv, wob);

    // fused QKV projection + RoPE + fragment-packing epilogue (counted-vmcnt pipeline)
    gemm_bt<<<dim3(32, 24), 256, 0, stream>>>(hb, wqkv, qbuf, HID, 3, 0, cosp, sinp);

    // flash attention: paired units, packed K/V (wave-linear fragment loads)
    attn_kernel<<<S_LEN / 64 * NH, 64, 0, stream>>>(qbuf, kpak, vpak, attn);

    // output projection -> fp32 (counted-vmcnt pipeline)
    gemm_bt<<<dim3(32, 16), 256, 0, stream>>>(attn, wob, out, HID, 1, HID, nullptr, nullptr);

    (void)in_sizes; (void)n_in; (void)out_size; (void)ws_size;
}

// Round 27
// 136.424 us; speedup vs baseline: 1.0015x; 1.0015x over previous
//
#include <hip/hip_runtime.h>
#include <hip/hip_bf16.h>

typedef unsigned short u16;
typedef __bf16 bf16x8 __attribute__((ext_vector_type(8)));
typedef float f32x4 __attribute__((ext_vector_type(4)));

#define S_LEN 2048
#define HID 2048
#define NH 32
#define NKV 8
#define HD 64

// native RTNE f32->bf16 (single v_cvt op; compiler packs pairs)
__device__ inline u16 f2bf(float x) {
    __bf16 h = (__bf16)x;
    return __builtin_bit_cast(u16, h);
}

__device__ inline void gload_lds16(const u16* g, u16* l) {
    __builtin_amdgcn_global_load_lds((const __attribute__((address_space(1))) unsigned int*)g,
                                     (__attribute__((address_space(3))) unsigned int*)l, 16, 0, 0);
}

// packed staging layout: fragment (fr, kc) = rows [fr*16, fr*16+16) x cols [kc*32, kc*32+32)
// stored contiguously (512 u16); within: lane = (row&15)*4 + ((col&31)>>3), elems col&7.
// u16 offset(row, col, K32) = ((fr*K32 + kc)*64 + (row&15)*4 + ((col&31)>>3))*8 + (col&7)

// ---------------- fp32 -> bf16 convert + fragment-pack, all 5 tensors ----------------
__global__ void cvt_all(const float* __restrict__ h, const float* __restrict__ wq,
                        const float* __restrict__ wk, const float* __restrict__ wv,
                        const float* __restrict__ wo,
                        u16* __restrict__ hb, u16* __restrict__ wqkv, u16* __restrict__ wob) {
    int i = blockIdx.x * blockDim.x + threadIdx.x;   // float4 index, total 3670016
    const float* src; u16* dst; int o; int rowoff = 0;
    if (i < 1048576)      { src = h;  dst = hb;   o = i; }
    else if (i < 2097152) { src = wq; dst = wqkv; o = i - 1048576; }
    else if (i < 2359296) { src = wk; dst = wqkv; o = i - 2097152; rowoff = 2048; }
    else if (i < 2621440) { src = wv; dst = wqkv; o = i - 2359296; rowoff = 2560; }
    else                  { src = wo; dst = wob;  o = i - 2621440; }
    float4 v = ((const float4*)src)[o];
    ushort4 u;
    u.x = f2bf(v.x); u.y = f2bf(v.y); u.z = f2bf(v.z); u.w = f2bf(v.w);
    // source element (row, col0..col0+3), K = 2048 (512 float4/row)
    const int row = (o >> 9) + rowoff;
    const int col0 = (o & 511) * 4;
    const int fr = row >> 4, r16w = row & 15;
    const int kc = col0 >> 5, gq = (col0 >> 3) & 3, e = col0 & 7;   // e in {0,4}
    u16* d = dst + ((size_t)(fr * 64 + kc) * 64 + r16w * 4 + gq) * 8 + e;
    *(ushort4*)d = u;   // 8B contiguous
}

// ---------------- GEMM: 64x128 tile, BK=32, double-buffered, packed staging ----------------
// All staging loads are wave-linear 1KB fragment reads (8 cache lines/instr).
// mode 1: store fp32 row-major (ldc); A = packed attn, B = packed wob
// mode 3: fused QKV epilogue with RoPE; K,V scattered into MFMA-fragment-packed layouts.
__global__ __launch_bounds__(256) void gemm_bt(const u16* __restrict__ Apk,
                                               const u16* __restrict__ Bpk,
                                               void* __restrict__ Cv,
                                               int K_, int mode, int ldc,
                                               const float* __restrict__ cosp,
                                               const float* __restrict__ sinp) {
    __shared__ u16 As[2][64 * 32];
    __shared__ u16 Bs[2][128 * 32];
    const int t = threadIdx.x;
    // XCD-aware bijective swizzle (nwg % 8 == 0 for both call sites)
    const int nwg = gridDim.x * gridDim.y;
    const int orig = blockIdx.y * gridDim.x + blockIdx.x;
    const int wgid = (orig & 7) * (nwg >> 3) + (orig >> 3);
    const int bm = wgid % gridDim.x, bn = wgid / gridDim.x;
    const int lane = t & 63, w = t >> 6;
    const int wr2 = (w >> 1) * 32, wc2 = (w & 1) * 64;
    const int g = lane >> 4, r16 = lane & 15;
    const int K32 = K_ >> 5;
    f32x4 acc[2][4] = {};

    // packed staging bases: A frag fr = bm*4 + w; B frags bn*8 + w*2, +1
    const u16* Ap = Apk + ((size_t)(bm * 4 + w) * K32) * 512 + lane * 8;
    const u16* Bp0 = Bpk + ((size_t)(bn * 8 + w * 2) * K32) * 512 + lane * 8;
    const u16* Bp1 = Bpk + ((size_t)(bn * 8 + w * 2 + 1) * K32) * 512 + lane * 8;
    const int aoff = w * 512;    // 16 rows * 32
    const int boff = w * 1024;   // 32 rows * 32

    // prologue: stage tile 0 into buffer 0
    gload_lds16(Ap, &As[0][aoff]);
    gload_lds16(Bp0, &Bs[0][boff]);
    gload_lds16(Bp1, &Bs[0][boff + 512]);
    __syncthreads();

    int cur = 0;
    for (int kc = 0; kc < K32; kc++) {
        if (kc + 1 < K32) {   // prefetch next K-step into the other buffer
            gload_lds16(Ap + (size_t)(kc + 1) * 512, &As[cur ^ 1][aoff]);
            gload_lds16(Bp0 + (size_t)(kc + 1) * 512, &Bs[cur ^ 1][boff]);
            gload_lds16(Bp1 + (size_t)(kc + 1) * 512, &Bs[cur ^ 1][boff + 512]);
        }
        bf16x8 af[2], bfr[4];
#pragma unroll
        for (int i = 0; i < 2; i++) af[i] = *(const bf16x8*)(&As[cur][(wr2 + i * 16 + r16) * 32 + g * 8]);
#pragma unroll
        for (int j = 0; j < 4; j++) bfr[j] = *(const bf16x8*)(&Bs[cur][(wc2 + j * 16 + r16) * 32 + g * 8]);
#pragma unroll
        for (int i = 0; i < 2; i++)
#pragma unroll
            for (int j = 0; j < 4; j++)
                acc[i][j] = __builtin_amdgcn_mfma_f32_16x16x32_bf16(af[i], bfr[j], acc[i][j], 0, 0, 0);
        __syncthreads();   // next-tile stage complete + all waves done reading cur
        cur ^= 1;
    }

    u16* qb_ = (u16*)Cv;
    u16* kb_ = qb_ + (size_t)2048 * 2048;
    u16* vt_ = kb_ + (size_t)512 * 2048;
    if (mode == 1) {
#pragma unroll
        for (int i = 0; i < 2; i++)
#pragma unroll
            for (int j = 0; j < 4; j++)
#pragma unroll
                for (int r = 0; r < 4; r++) {
                    int row = bm * 64 + wr2 + i * 16 + g * 4 + r;
                    int col = bn * 128 + wc2 + j * 16 + r16;
                    ((float*)Cv)[(size_t)row * ldc + col] = acc[i][j][r];
                }
    } else {
        const int cbase = bn * 128 + wc2;   // 64-aligned => wave span = one head
        if (cbase < 2560) {
            // q or k region: fused RoPE on fp32 accumulators (exact pre-round)
            const float scl = (cbase < 2048) ? 0.125f * 1.44269504f : 1.0f;
#pragma unroll
            for (int i = 0; i < 2; i++)
#pragma unroll
                for (int r = 0; r < 4; r++) {
                    int row = bm * 64 + wr2 + i * 16 + g * 4 + r;
#pragma unroll
                    for (int j = 0; j < 2; j++) {
                        int c0 = cbase + j * 16 + r16;
                        int iin = c0 & 63;                 // in-head dim, < 32
                        float x1 = acc[i][j][r], x2 = acc[i][j + 2][r];
                        float cA = cosp[row * 64 + iin],      sA = sinp[row * 64 + iin];
                        float cB = cosp[row * 64 + iin + 32], sB = sinp[row * 64 + iin + 32];
                        u16 o1 = f2bf((x1 * cA - x2 * sA) * scl);
                        u16 o2 = f2bf((x2 * cB + x1 * sB) * scl);
                        if (cbase < 2048) {
                            qb_[(size_t)row * 2048 + c0] = o1;
                            qb_[(size_t)row * 2048 + c0 + 32] = o2;
                        } else {
                            // K fragment-packed: frag row fr = row>>4, lane = gq*16 + (row&15)
                            int c = c0 - 2048;
                            int kvh_w = c >> 6, iin2 = c & 63;
                            int gq = (iin2 >> 3) & 3, e = iin2 & 7;
                            int fr = row >> 4, r16w = row & 15;
                            size_t base = ((size_t)(kvh_w * 128 + fr) * 2) * 512 + (size_t)(gq * 16 + r16w) * 8 + e;
                            kb_[base] = o1;            // d=0 (iin<32)
                            kb_[base + 512] = o2;      // d=1 (iin+32)
                        }
                    }
                }
        } else {
            // V fragment-packed: dg = col-2560; s = row
#pragma unroll
            for (int i = 0; i < 2; i++)
#pragma unroll
                for (int j = 0; j < 4; j++)
#pragma unroll
                    for (int r = 0; r < 4; r++) {
                        int row = bm * 64 + wr2 + i * 16 + g * 4 + r;
                        int col = cbase + j * 16 + r16;
                        int dg = col - 2560;
                        int kvh_w = dg >> 6, dblk_w = (dg >> 4) & 3, r16v = dg & 15;
                        int fr32 = row >> 5, gv = (row >> 3) & 3, e = row & 7;
                        vt_[((size_t)((kvh_w * 64 + fr32) * 4 + dblk_w)) * 512 + (size_t)(gv * 16 + r16v) * 8 + e] = f2bf(acc[i][j][r]);
                    }
        }
    }
}

// ---------------- Flash attention (causal, GQA): paired units, packed K/V ----------------
// R24-proven: wave-linear 1KB fragment loads, shift-free softmax, raw exp2,
// l rides MFMA ones-column, kvh-per-XCD, paired units (63-p then p).
// Output written in packed staging layout for the O-projection's A operand.
__global__ __launch_bounds__(64) void attn_kernel(const u16* __restrict__ q,
                                                  const u16* __restrict__ kp_all,
                                                  const u16* __restrict__ vp_all,
                                                  u16* __restrict__ attn_pk) {
    __shared__ u16 P[2][16][136];  // [frag][qrow][kcol]
    const int bid = blockIdx.x;
    const int kvh = bid & 7;                       // XCD-local KV slice
    const int h = kvh * 4 + ((bid >> 3) & 3);
    const int p = bid >> 5;                        // 0..31 pair index
    const int lane = threadIdx.x & 63;
    const int g = lane >> 4, r16 = lane & 15;

    const u16* kp = kp_all + (size_t)kvh * 131072;   // 128 frags * 2 d * 512
    const u16* vp = vp_all + (size_t)kvh * 131072;   // 64 frags * 4 dblk * 512

    bf16x8 vone;
#pragma unroll
    for (int j = 0; j < 8; j++) vone[j] = (__bf16)1.0f;

    for (int u = 0; u < 2; u++) {
        const int qblk = u ? p : 63 - p;   // heavy unit first
        const int qrow0 = qblk * 32;

        bf16x8 qf[2][2];
#pragma unroll
        for (int fi = 0; fi < 2; fi++)
#pragma unroll
            for (int d = 0; d < 2; d++)
                qf[fi][d] = *(const bf16x8*)(q + (size_t)(qrow0 + fi * 16 + r16) * (NH * HD) + h * HD + d * 32 + g * 8);

        f32x4 o[2][4] = {};
        f32x4 ol[2] = {};   // l ridden as an MFMA ones-column

        const int last = (qrow0 >> 7) << 7;   // last 128-wide KV tile start

        // prologue: load K tile 0 (packed: frag fr, lane-linear)
        bf16x8 kA[4][2], kB[4][2];
#pragma unroll
        for (int s4 = 0; s4 < 4; s4++)
#pragma unroll
            for (int d = 0; d < 2; d++) {
                kA[s4][d] = *(const bf16x8*)(kp + ((size_t)(s4 * 2 + d)) * 512 + lane * 8);
                kB[s4][d] = *(const bf16x8*)(kp + ((size_t)((4 + s4) * 2 + d)) * 512 + lane * 8);
            }

        for (int kv = 0; kv <= last; kv += 128) {
            const bool diag = (kv == last);
            f32x4 sacc[2][8] = {};
            // ---- QK^T: 32 MFMA on registered K tile ----
#pragma unroll
            for (int s4 = 0; s4 < 4; s4++)
#pragma unroll
                for (int fi = 0; fi < 2; fi++)
#pragma unroll
                    for (int d = 0; d < 2; d++)
                        sacc[fi][s4] = __builtin_amdgcn_mfma_f32_16x16x32_bf16(qf[fi][d], kA[s4][d], sacc[fi][s4], 0, 0, 0);
#pragma unroll
            for (int s4 = 0; s4 < 4; s4++)
#pragma unroll
                for (int fi = 0; fi < 2; fi++)
#pragma unroll
                    for (int d = 0; d < 2; d++)
                        sacc[fi][4 + s4] = __builtin_amdgcn_mfma_f32_16x16x32_bf16(qf[fi][d], kB[s4][d], sacc[fi][4 + s4], 0, 0, 0);
            // ---- prefetch next K tile (packed) ----
            if (kv + 128 <= last) {
                const int nf = (kv + 128) >> 4;   // next tile's first frag
#pragma unroll
                for (int s4 = 0; s4 < 4; s4++)
#pragma unroll
                    for (int d = 0; d < 2; d++) {
                        kA[s4][d] = *(const bf16x8*)(kp + ((size_t)((nf + s4) * 2 + d)) * 512 + lane * 8);
                        kB[s4][d] = *(const bf16x8*)(kp + ((size_t)((nf + 4 + s4) * 2 + d)) * 512 + lane * 8);
                    }
            }
            // ---- V loads (packed): frag fv = kv/32 + kq ----
            bf16x8 vf[4][4];
            const int fv0 = kv >> 5;
#pragma unroll
            for (int kq = 0; kq < 4; kq++)
#pragma unroll
                for (int dblk = 0; dblk < 4; dblk++)
                    vf[kq][dblk] = *(const bf16x8*)(vp + ((size_t)((fv0 + kq) * 4 + dblk)) * 512 + lane * 8);
            // ---- causal mask (diagonal super-tile only): exp2(-1e30) -> 0 ----
            if (diag) {
#pragma unroll
                for (int fi = 0; fi < 2; fi++)
#pragma unroll
                    for (int sub = 0; sub < 8; sub++)
#pragma unroll
                        for (int r = 0; r < 4; r++) {
                            int col = kv + sub * 16 + r16;
                            int row = qrow0 + fi * 16 + g * 4 + r;
                            if (col > row) sacc[fi][sub][r] = -1e30f;
                        }
            }
            // ---- shift-free softmax numerator: P = exp2(S) straight to LDS ----
#pragma unroll
            for (int fi = 0; fi < 2; fi++)
#pragma unroll
                for (int sub = 0; sub < 8; sub++)
#pragma unroll
                    for (int r = 0; r < 4; r++)
                        P[fi][g * 4 + r][sub * 16 + r16] = f2bf(__builtin_amdgcn_exp2f(sacc[fi][sub][r]));
            // ---- PV: 40 MFMA (4 dblk + 1 ones-column per kq per frag) ----
#pragma unroll
            for (int fi = 0; fi < 2; fi++)
#pragma unroll
                for (int kq = 0; kq < 4; kq++) {
                    bf16x8 pf = *(const bf16x8*)(&P[fi][r16][kq * 32 + g * 8]);
                    ol[fi] = __builtin_amdgcn_mfma_f32_16x16x32_bf16(pf, vone, ol[fi], 0, 0, 0);
#pragma unroll
                    for (int dblk = 0; dblk < 4; dblk++)
                        o[fi][dblk] = __builtin_amdgcn_mfma_f32_16x16x32_bf16(pf, vf[kq][dblk], o[fi][dblk], 0, 0, 0);
                }
        }
        // ---- unit epilogue: write packed staging layout for O-proj A ----
        // row = qrow0 + fi*16 + g*4 + r  -> fr = qblk*2+fi, row&15 = g*4+r
        // col = h*64 + dblk*16 + r16     -> kc = h*2 + (dblk>>1)
#pragma unroll
        for (int fi = 0; fi < 2; fi++) {
            float inv[4];
#pragma unroll
            for (int r = 0; r < 4; r++) inv[r] = 1.0f / ol[fi][r];
            const int fr = qblk * 2 + fi;
#pragma unroll
            for (int dblk = 0; dblk < 4; dblk++) {
                const int kc = h * 2 + (dblk >> 1);
                const int ls_base = (dblk & 1) * 2 + (r16 >> 3);
                const int e = r16 & 7;
#pragma unroll
                for (int r = 0; r < 4; r++) {
                    float val = o[fi][dblk][r] * inv[r];
                    attn_pk[((size_t)(fr * 64 + kc) * 64 + (g * 4 + r) * 4 + ls_base) * 8 + e] = f2bf(val);
                }
            }
        }
    }
}

extern "C" void kernel_launch(void* const* d_in, const int* in_sizes, int n_in,
                              void* d_out, int out_size, void* d_ws, size_t ws_size,
                              hipStream_t stream) {
    const float* hidden = (const float*)d_in[0];
    const float* Wq = (const float*)d_in[1];
    const float* Wk = (const float*)d_in[2];
    const float* Wv = (const float*)d_in[3];
    const float* Wo = (const float*)d_in[4];
    const float* cosp = (const float*)d_in[5];
    const float* sinp = (const float*)d_in[6];
    float* out = (float*)d_out;

    char* ws = (char*)d_ws;
    u16* hb   = (u16*)(ws);                        // 8 MB  packed [2048,2048]
    u16* wqkv = (u16*)(ws + ((size_t)8 << 20));    // 12 MB packed [3072,2048]
    u16* wob  = (u16*)(ws + ((size_t)20 << 20));   // 8 MB  packed [2048,2048]
    u16* qbuf = (u16*)(ws + ((size_t)28 << 20));   // 8 MB  row-major [2048,2048]
    u16* kpak = qbuf + (size_t)2048 * 2048;        // 2 MB  fragment-packed K
    u16* vpak = kpak + (size_t)512 * 2048;         // 2 MB  fragment-packed V
    u16* atpk = (u16*)(ws + ((size_t)40 << 20));   // 8 MB  packed attn output

    // fused fp32->bf16 conversion + fragment packing
    cvt_all<<<14336, 256, 0, stream>>>(hidden, Wq, Wk, Wv, Wo, hb, wqkv, wob);

    // fused QKV projection + RoPE + fragment-packing epilogue (packed staging)
    gemm_bt<<<dim3(32, 24), 256, 0, stream>>>(hb, wqkv, qbuf, HID, 3, 0, cosp, sinp);

    // flash attention: paired units, packed K/V in, packed output
    attn_kernel<<<S_LEN / 64 * NH, 64, 0, stream>>>(qbuf, kpak, vpak, atpk);

    // output projection -> fp32 (packed staging)
    gemm_bt<<<dim3(32, 16), 256, 0, stream>>>(atpk, wob, out, HID, 1, HID, nullptr, nullptr);

    (void)in_sizes; (void)n_in; (void)out_size; (void)ws_size;
}

// Round 28
// 121.042 us; speedup vs baseline: 1.1288x; 1.1271x over previous
//
#include <hip/hip_runtime.h>
#include <hip/hip_bf16.h>

typedef unsigned short u16;
typedef __bf16 bf16x8 __attribute__((ext_vector_type(8)));
typedef float f32x4 __attribute__((ext_vector_type(4)));

#define S_LEN 2048
#define HID 2048
#define NH 32
#define NKV 8
#define HD 64

// native RTNE f32->bf16 (single v_cvt op; compiler packs pairs)
__device__ inline u16 f2bf(float x) {
    __bf16 h = (__bf16)x;
    return __builtin_bit_cast(u16, h);
}

__device__ inline void gload_lds16(const u16* g, u16* l) {
    __builtin_amdgcn_global_load_lds((const __attribute__((address_space(1))) unsigned int*)g,
                                     (__attribute__((address_space(3))) unsigned int*)l, 16, 0, 0);
}

// packed staging layout: fragment (fr, kc) = rows [fr*16, fr*16+16) x cols [kc*32, kc*32+32)
// stored contiguously (512 u16); within: lane = (row&15)*4 + ((col&31)>>3), elems col&7.

// ---------------- fp32 -> bf16 convert + fragment-pack, all 5 tensors ----------------
__global__ void cvt_all(const float* __restrict__ h, const float* __restrict__ wq,
                        const float* __restrict__ wk, const float* __restrict__ wv,
                        const float* __restrict__ wo,
                        u16* __restrict__ hb, u16* __restrict__ wqkv, u16* __restrict__ wob) {
    int i = blockIdx.x * blockDim.x + threadIdx.x;   // float4 index, total 3670016
    const float* src; u16* dst; int o; int rowoff = 0;
    if (i < 1048576)      { src = h;  dst = hb;   o = i; }
    else if (i < 2097152) { src = wq; dst = wqkv; o = i - 1048576; }
    else if (i < 2359296) { src = wk; dst = wqkv; o = i - 2097152; rowoff = 2048; }
    else if (i < 2621440) { src = wv; dst = wqkv; o = i - 2359296; rowoff = 2560; }
    else                  { src = wo; dst = wob;  o = i - 2621440; }
    float4 v = ((const float4*)src)[o];
    ushort4 u;
    u.x = f2bf(v.x); u.y = f2bf(v.y); u.z = f2bf(v.z); u.w = f2bf(v.w);
    // source element (row, col0..col0+3), K = 2048 (512 float4/row)
    const int row = (o >> 9) + rowoff;
    const int col0 = (o & 511) * 4;
    const int fr = row >> 4, r16w = row & 15;
    const int kc = col0 >> 5, gq = (col0 >> 3) & 3, e = col0 & 7;   // e in {0,4}
    u16* d = dst + ((size_t)(fr * 64 + kc) * 64 + r16w * 4 + gq) * 8 + e;
    *(ushort4*)d = u;   // 8B contiguous
}

// ---------------- GEMM: 64x128 tile, BK=64 (2 fragments/step), double-buffered ----------------
// Fragment-packed staging (wave-linear 1KB gloads) + fragment-packed LDS:
// per-fragment contiguous 1KB blocks -> 64B row stride regardless of BK (no R11 conflicts).
// 32 barrier-steps instead of 64.
// mode 1: store fp32 row-major (ldc); mode 3: fused QKV epilogue with RoPE + K/V packing.
__global__ __launch_bounds__(256) void gemm_bt(const u16* __restrict__ Apk,
                                               const u16* __restrict__ Bpk,
                                               void* __restrict__ Cv,
                                               int K_, int mode, int ldc,
                                               const float* __restrict__ cosp,
                                               const float* __restrict__ sinp) {
    __shared__ u16 As[2][8 * 512];    // 4 row-frags x 2 kc, frag_lin = fr*2+kc
    __shared__ u16 Bs[2][16 * 512];   // 8 row-frags x 2 kc
    const int t = threadIdx.x;
    // XCD-aware bijective swizzle (nwg % 8 == 0 for both call sites)
    const int nwg = gridDim.x * gridDim.y;
    const int orig = blockIdx.y * gridDim.x + blockIdx.x;
    const int wgid = (orig & 7) * (nwg >> 3) + (orig >> 3);
    const int bm = wgid % gridDim.x, bn = wgid / gridDim.x;
    const int lane = t & 63, w = t >> 6;
    const int wr2 = (w >> 1) * 32, wc2 = (w & 1) * 64;
    const int g = lane >> 4, r16 = lane & 15;
    const int K32 = K_ >> 5;
    const int nst = K_ >> 6;          // 64-wide K steps
    f32x4 acc[2][4] = {};

    // packed staging bases: A frag-row bm*4 + w; B frag-rows bn*8 + 2w, +1
    const u16* Ap = Apk + ((size_t)(bm * 4 + w) * K32) * 512 + lane * 8;
    const u16* Bp0 = Bpk + ((size_t)(bn * 8 + w * 2) * K32) * 512 + lane * 8;
    const u16* Bp1 = Bpk + ((size_t)(bn * 8 + w * 2 + 1) * K32) * 512 + lane * 8;

    // prologue: stage step 0 into buffer 0
#pragma unroll
    for (int kc = 0; kc < 2; kc++) {
        gload_lds16(Ap + (size_t)kc * 512, &As[0][(w * 2 + kc) * 512]);
        gload_lds16(Bp0 + (size_t)kc * 512, &Bs[0][(w * 4 + kc) * 512]);
        gload_lds16(Bp1 + (size_t)kc * 512, &Bs[0][(w * 4 + 2 + kc) * 512]);
    }
    __syncthreads();

    int cur = 0;
    for (int st = 0; st < nst; st++) {
        if (st + 1 < nst) {   // prefetch next step into the other buffer
            const size_t nb = (size_t)(st + 1) * 2;
#pragma unroll
            for (int kc = 0; kc < 2; kc++) {
                gload_lds16(Ap + (nb + kc) * 512, &As[cur ^ 1][(w * 2 + kc) * 512]);
                gload_lds16(Bp0 + (nb + kc) * 512, &Bs[cur ^ 1][(w * 4 + kc) * 512]);
                gload_lds16(Bp1 + (nb + kc) * 512, &Bs[cur ^ 1][(w * 4 + 2 + kc) * 512]);
            }
        }
#pragma unroll
        for (int kc = 0; kc < 2; kc++) {
            bf16x8 af[2], bfr[4];
#pragma unroll
            for (int i = 0; i < 2; i++)
                af[i] = *(const bf16x8*)(&As[cur][(((w >> 1) * 2 + i) * 2 + kc) * 512 + r16 * 32 + g * 8]);
#pragma unroll
            for (int j = 0; j < 4; j++)
                bfr[j] = *(const bf16x8*)(&Bs[cur][(((w & 1) * 4 + j) * 2 + kc) * 512 + r16 * 32 + g * 8]);
#pragma unroll
            for (int i = 0; i < 2; i++)
#pragma unroll
                for (int j = 0; j < 4; j++)
                    acc[i][j] = __builtin_amdgcn_mfma_f32_16x16x32_bf16(af[i], bfr[j], acc[i][j], 0, 0, 0);
        }
        __syncthreads();   // next-step stage complete + all waves done reading cur
        cur ^= 1;
    }

    u16* qb_ = (u16*)Cv;
    u16* kb_ = qb_ + (size_t)2048 * 2048;
    u16* vt_ = kb_ + (size_t)512 * 2048;
    if (mode == 1) {
#pragma unroll
        for (int i = 0; i < 2; i++)
#pragma unroll
            for (int j = 0; j < 4; j++)
#pragma unroll
                for (int r = 0; r < 4; r++) {
                    int row = bm * 64 + wr2 + i * 16 + g * 4 + r;
                    int col = bn * 128 + wc2 + j * 16 + r16;
                    ((float*)Cv)[(size_t)row * ldc + col] = acc[i][j][r];
                }
    } else {
        const int cbase = bn * 128 + wc2;   // 64-aligned => wave span = one head
        if (cbase < 2560) {
            // q or k region: fused RoPE on fp32 accumulators (exact pre-round)
            const float scl = (cbase < 2048) ? 0.125f * 1.44269504f : 1.0f;
#pragma unroll
            for (int i = 0; i < 2; i++)
#pragma unroll
                for (int r = 0; r < 4; r++) {
                    int row = bm * 64 + wr2 + i * 16 + g * 4 + r;
#pragma unroll
                    for (int j = 0; j < 2; j++) {
                        int c0 = cbase + j * 16 + r16;
                        int iin = c0 & 63;                 // in-head dim, < 32
                        float x1 = acc[i][j][r], x2 = acc[i][j + 2][r];
                        float cA = cosp[row * 64 + iin],      sA = sinp[row * 64 + iin];
                        float cB = cosp[row * 64 + iin + 32], sB = sinp[row * 64 + iin + 32];
                        u16 o1 = f2bf((x1 * cA - x2 * sA) * scl);
                        u16 o2 = f2bf((x2 * cB + x1 * sB) * scl);
                        if (cbase < 2048) {
                            qb_[(size_t)row * 2048 + c0] = o1;
                            qb_[(size_t)row * 2048 + c0 + 32] = o2;
                        } else {
                            // K fragment-packed: frag row fr = row>>4, lane = gq*16 + (row&15)
                            int c = c0 - 2048;
                            int kvh_w = c >> 6, iin2 = c & 63;
                            int gq = (iin2 >> 3) & 3, e = iin2 & 7;
                            int fr = row >> 4, r16w = row & 15;
                            size_t base = ((size_t)(kvh_w * 128 + fr) * 2) * 512 + (size_t)(gq * 16 + r16w) * 8 + e;
                            kb_[base] = o1;            // d=0 (iin<32)
                            kb_[base + 512] = o2;      // d=1 (iin+32)
                        }
                    }
                }
        } else {
            // V fragment-packed: dg = col-2560; s = row
#pragma unroll
            for (int i = 0; i < 2; i++)
#pragma unroll
                for (int j = 0; j < 4; j++)
#pragma unroll
                    for (int r = 0; r < 4; r++) {
                        int row = bm * 64 + wr2 + i * 16 + g * 4 + r;
                        int col = cbase + j * 16 + r16;
                        int dg = col - 2560;
                        int kvh_w = dg >> 6, dblk_w = (dg >> 4) & 3, r16v = dg & 15;
                        int fr32 = row >> 5, gv = (row >> 3) & 3, e = row & 7;
                        vt_[((size_t)((kvh_w * 64 + fr32) * 4 + dblk_w)) * 512 + (size_t)(gv * 16 + r16v) * 8 + e] = f2bf(acc[i][j][r]);
                    }
        }
    }
}

// ---------------- Flash attention (causal, GQA): paired units, packed K/V ----------------
// R24-proven: wave-linear 1KB fragment loads, shift-free softmax, raw exp2,
// l rides MFMA ones-column, kvh-per-XCD, paired units (63-p then p).
// Output written in packed staging layout for the O-projection's A operand.
__global__ __launch_bounds__(64) void attn_kernel(const u16* __restrict__ q,
                                                  const u16* __restrict__ kp_all,
                                                  const u16* __restrict__ vp_all,
                                                  u16* __restrict__ attn_pk) {
    __shared__ u16 P[2][16][136];  // [frag][qrow][kcol]
    const int bid = blockIdx.x;
    const int kvh = bid & 7;                       // XCD-local KV slice
    const int h = kvh * 4 + ((bid >> 3) & 3);
    const int p = bid >> 5;                        // 0..31 pair index
    const int lane = threadIdx.x & 63;
    const int g = lane >> 4, r16 = lane & 15;

    const u16* kp = kp_all + (size_t)kvh * 131072;   // 128 frags * 2 d * 512
    const u16* vp = vp_all + (size_t)kvh * 131072;   // 64 frags * 4 dblk * 512

    bf16x8 vone;
#pragma unroll
    for (int j = 0; j < 8; j++) vone[j] = (__bf16)1.0f;

    for (int u = 0; u < 2; u++) {
        const int qblk = u ? p : 63 - p;   // heavy unit first
        const int qrow0 = qblk * 32;

        bf16x8 qf[2][2];
#pragma unroll
        for (int fi = 0; fi < 2; fi++)
#pragma unroll
            for (int d = 0; d < 2; d++)
                qf[fi][d] = *(const bf16x8*)(q + (size_t)(qrow0 + fi * 16 + r16) * (NH * HD) + h * HD + d * 32 + g * 8);

        f32x4 o[2][4] = {};
        f32x4 ol[2] = {};   // l ridden as an MFMA ones-column

        const int last = (qrow0 >> 7) << 7;   // last 128-wide KV tile start

        // prologue: load K tile 0 (packed: frag fr, lane-linear)
        bf16x8 kA[4][2], kB[4][2];
#pragma unroll
        for (int s4 = 0; s4 < 4; s4++)
#pragma unroll
            for (int d = 0; d < 2; d++) {
                kA[s4][d] = *(const bf16x8*)(kp + ((size_t)(s4 * 2 + d)) * 512 + lane * 8);
                kB[s4][d] = *(const bf16x8*)(kp + ((size_t)((4 + s4) * 2 + d)) * 512 + lane * 8);
            }

        for (int kv = 0; kv <= last; kv += 128) {
            const bool diag = (kv == last);
            f32x4 sacc[2][8] = {};
            // ---- QK^T: 32 MFMA on registered K tile ----
#pragma unroll
            for (int s4 = 0; s4 < 4; s4++)
#pragma unroll
                for (int fi = 0; fi < 2; fi++)
#pragma unroll
                    for (int d = 0; d < 2; d++)
                        sacc[fi][s4] = __builtin_amdgcn_mfma_f32_16x16x32_bf16(qf[fi][d], kA[s4][d], sacc[fi][s4], 0, 0, 0);
#pragma unroll
            for (int s4 = 0; s4 < 4; s4++)
#pragma unroll
                for (int fi = 0; fi < 2; fi++)
#pragma unroll
                    for (int d = 0; d < 2; d++)
                        sacc[fi][4 + s4] = __builtin_amdgcn_mfma_f32_16x16x32_bf16(qf[fi][d], kB[s4][d], sacc[fi][4 + s4], 0, 0, 0);
            // ---- prefetch next K tile (packed) ----
            if (kv + 128 <= last) {
                const int nf = (kv + 128) >> 4;   // next tile's first frag
#pragma unroll
                for (int s4 = 0; s4 < 4; s4++)
#pragma unroll
                    for (int d = 0; d < 2; d++) {
                        kA[s4][d] = *(const bf16x8*)(kp + ((size_t)((nf + s4) * 2 + d)) * 512 + lane * 8);
                        kB[s4][d] = *(const bf16x8*)(kp + ((size_t)((nf + 4 + s4) * 2 + d)) * 512 + lane * 8);
                    }
            }
            // ---- V loads (packed): frag fv = kv/32 + kq ----
            bf16x8 vf[4][4];
            const int fv0 = kv >> 5;
#pragma unroll
            for (int kq = 0; kq < 4; kq++)
#pragma unroll
                for (int dblk = 0; dblk < 4; dblk++)
                    vf[kq][dblk] = *(const bf16x8*)(vp + ((size_t)((fv0 + kq) * 4 + dblk)) * 512 + lane * 8);
            // ---- causal mask (diagonal super-tile only): exp2(-1e30) -> 0 ----
            if (diag) {
#pragma unroll
                for (int fi = 0; fi < 2; fi++)
#pragma unroll
                    for (int sub = 0; sub < 8; sub++)
#pragma unroll
                        for (int r = 0; r < 4; r++) {
                            int col = kv + sub * 16 + r16;
                            int row = qrow0 + fi * 16 + g * 4 + r;
                            if (col > row) sacc[fi][sub][r] = -1e30f;
                        }
            }
            // ---- shift-free softmax numerator: P = exp2(S) straight to LDS ----
#pragma unroll
            for (int fi = 0; fi < 2; fi++)
#pragma unroll
                for (int sub = 0; sub < 8; sub++)
#pragma unroll
                    for (int r = 0; r < 4; r++)
                        P[fi][g * 4 + r][sub * 16 + r16] = f2bf(__builtin_amdgcn_exp2f(sacc[fi][sub][r]));
            // ---- PV: 40 MFMA (4 dblk + 1 ones-column per kq per frag) ----
#pragma unroll
            for (int fi = 0; fi < 2; fi++)
#pragma unroll
                for (int kq = 0; kq < 4; kq++) {
                    bf16x8 pf = *(const bf16x8*)(&P[fi][r16][kq * 32 + g * 8]);
                    ol[fi] = __builtin_amdgcn_mfma_f32_16x16x32_bf16(pf, vone, ol[fi], 0, 0, 0);
#pragma unroll
                    for (int dblk = 0; dblk < 4; dblk++)
                        o[fi][dblk] = __builtin_amdgcn_mfma_f32_16x16x32_bf16(pf, vf[kq][dblk], o[fi][dblk], 0, 0, 0);
                }
        }
        // ---- unit epilogue: write packed staging layout for O-proj A ----
#pragma unroll
        for (int fi = 0; fi < 2; fi++) {
            float inv[4];
#pragma unroll
            for (int r = 0; r < 4; r++) inv[r] = 1.0f / ol[fi][r];
            const int fr = qblk * 2 + fi;
#pragma unroll
            for (int dblk = 0; dblk < 4; dblk++) {
                const int kc = h * 2 + (dblk >> 1);
                const int ls_base = (dblk & 1) * 2 + (r16 >> 3);
                const int e = r16 & 7;
#pragma unroll
                for (int r = 0; r < 4; r++) {
                    float val = o[fi][dblk][r] * inv[r];
                    attn_pk[((size_t)(fr * 64 + kc) * 64 + (g * 4 + r) * 4 + ls_base) * 8 + e] = f2bf(val);
                }
            }
        }
    }
}

extern "C" void kernel_launch(void* const* d_in, const int* in_sizes, int n_in,
                              void* d_out, int out_size, void* d_ws, size_t ws_size,
                              hipStream_t stream) {
    const float* hidden = (const float*)d_in[0];
    const float* Wq = (const float*)d_in[1];
    const float* Wk = (const float*)d_in[2];
    const float* Wv = (const float*)d_in[3];
    const float* Wo = (const float*)d_in[4];
    const float* cosp = (const float*)d_in[5];
    const float* sinp = (const float*)d_in[6];
    float* out = (float*)d_out;

    char* ws = (char*)d_ws;
    u16* hb   = (u16*)(ws);                        // 8 MB  packed [2048,2048]
    u16* wqkv = (u16*)(ws + ((size_t)8 << 20));    // 12 MB packed [3072,2048]
    u16* wob  = (u16*)(ws + ((size_t)20 << 20));   // 8 MB  packed [2048,2048]
    u16* qbuf = (u16*)(ws + ((size_t)28 << 20));   // 8 MB  row-major [2048,2048]
    u16* kpak = qbuf + (size_t)2048 * 2048;        // 2 MB  fragment-packed K
    u16* vpak = kpak + (size_t)512 * 2048;         // 2 MB  fragment-packed V
    u16* atpk = (u16*)(ws + ((size_t)40 << 20));   // 8 MB  packed attn output

    // fused fp32->bf16 conversion + fragment packing
    cvt_all<<<14336, 256, 0, stream>>>(hidden, Wq, Wk, Wv, Wo, hb, wqkv, wob);

    // fused QKV projection + RoPE + fragment-packing epilogue (BK=64, packed staging)
    gemm_bt<<<dim3(32, 24), 256, 0, stream>>>(hb, wqkv, qbuf, HID, 3, 0, cosp, sinp);

    // flash attention: paired units, packed K/V in, packed output
    attn_kernel<<<S_LEN / 64 * NH, 64, 0, stream>>>(qbuf, kpak, vpak, atpk);

    // output projection -> fp32 (BK=64, packed staging)
    gemm_bt<<<dim3(32, 16), 256, 0, stream>>>(atpk, wob, out, HID, 1, HID, nullptr, nullptr);

    (void)in_sizes; (void)n_in; (void)out_size; (void)ws_size;
}